// Round 4
// baseline (534.385 us; speedup 1.0000x reference)
//
#include <hip/hip_runtime.h>
#include <cstdint>
#include <cstddef>

typedef unsigned short u16;
typedef __attribute__((ext_vector_type(8))) short short8;
typedef __attribute__((ext_vector_type(4))) float floatx4;
typedef __attribute__((ext_vector_type(4))) unsigned int uintx4;

__device__ __forceinline__ float bf2f(u16 u){
  union { unsigned int i; float f; } v; v.i = ((unsigned int)u) << 16; return v.f;
}
__device__ __forceinline__ u16 f2bf(float f){
  union { float ff; unsigned int i; } v; v.ff = f;
  return (u16)((v.i + 0x7fffu + ((v.i >> 16) & 1u)) >> 16);
}
__device__ __forceinline__ unsigned int pk2(float a, float b){
  return (unsigned int)f2bf(a) | ((unsigned int)f2bf(b) << 16);
}
// read 32 bf16 (internal buffers) -> 32 floats
__device__ __forceinline__ void load32(const u16* p, float* v){
  const uintx4* p4 = (const uintx4*)p;
#pragma unroll
  for (int c = 0; c < 4; ++c){
    uintx4 u = p4[c];
    v[c*8+0] = bf2f((u16)(u.x & 0xffffu)); v[c*8+1] = bf2f((u16)(u.x >> 16));
    v[c*8+2] = bf2f((u16)(u.y & 0xffffu)); v[c*8+3] = bf2f((u16)(u.y >> 16));
    v[c*8+4] = bf2f((u16)(u.z & 0xffffu)); v[c*8+5] = bf2f((u16)(u.z >> 16));
    v[c*8+6] = bf2f((u16)(u.w & 0xffffu)); v[c*8+7] = bf2f((u16)(u.w >> 16));
  }
}
// L2-normalize a 32-vector, store bf16 in k-outer layout [4][R][8]
__device__ __forceinline__ void norm_store(u16* dst, const float* v, int t, int strideU16){
  float ss = 0.f;
#pragma unroll
  for (int e = 0; e < 32; ++e) ss += v[e]*v[e];
  float inv = 1.f / fmaxf(sqrtf(ss), 1e-12f);
#pragma unroll
  for (int q = 0; q < 4; ++q){
    uintx4 u;
    u.x = pk2(v[q*8+0]*inv, v[q*8+1]*inv);
    u.y = pk2(v[q*8+2]*inv, v[q*8+3]*inv);
    u.z = pk2(v[q*8+4]*inv, v[q*8+5]*inv);
    u.w = pk2(v[q*8+6]*inv, v[q*8+7]*inv);
    *(uintx4*)(dst + q*strideU16 + t*8) = u;
  }
}
__device__ __forceinline__ float rsum16(float v){
  v += __shfl_xor(v, 1, 16); v += __shfl_xor(v, 2, 16);
  v += __shfl_xor(v, 4, 16); v += __shfl_xor(v, 8, 16);
  return v;
}
__device__ __forceinline__ float expc(float a){   // clamped exp: never inf
  return __expf(fminf(a, 30.f));
}
// load 8 fp32 from g, convert to 8 bf16 packed in a uintx4
__device__ __forceinline__ uintx4 ld8f_bf(const float* g){
  floatx4 u0 = *(const floatx4*)g;
  floatx4 u1 = *(const floatx4*)(g + 4);
  uintx4 w;
  w.x = pk2(u0.x, u0.y); w.y = pk2(u0.z, u0.w);
  w.z = pk2(u1.x, u1.y); w.w = pk2(u1.z, u1.w);
  return w;
}

// ---------------- prep kernels ----------------
__global__ void transpose_w(const float* __restrict__ qkv_w, const float* __restrict__ anchor_w,
                            const float* __restrict__ proj_w,
                            u16* __restrict__ qkvt, u16* __restrict__ anct, u16* __restrict__ projt){
  int id = blockIdx.x*256 + threadIdx.x;
  if (id < 196608){ int k = id / 768, n = id % 768; qkvt[n*256 + k] = f2bf(qkv_w[id]); }
  else if (id < 229376){ int r = id - 196608; int k = r / 128, n = r % 128; anct[n*256 + k] = f2bf(anchor_w[r]); }
  else { int r = id - 229376; int k = r >> 8, n = r & 255; projt[n*256 + k] = f2bf(proj_w[r]); }
}

__global__ void cpb_mlp(const float* __restrict__ tw, const float* __restrict__ ts,
                        const float* __restrict__ w1w, const float* __restrict__ b1w, const float* __restrict__ w2w,
                        const float* __restrict__ w1s1, const float* __restrict__ b1s1, const float* __restrict__ w2s1,
                        const float* __restrict__ w1s2, const float* __restrict__ b1s2, const float* __restrict__ w2s2,
                        float* __restrict__ btw, float* __restrict__ bts1, float* __restrict__ bts2){
  int tag = blockIdx.y;
  const float *tab, *w1, *b1, *w2; float* bt; int T;
  if (tag == 0){ tab = tw; w1 = w1w;  b1 = b1w;  w2 = w2w;  bt = btw;  T = 961; }
  else if (tag == 1){ tab = ts; w1 = w1s1; b1 = b1s1; w2 = w2s1; bt = bts1; T = 1521; }
  else { tab = ts; w1 = w1s2; b1 = b1s2; w2 = w2s2; bt = bts2; T = 1521; }
  __shared__ float sw1[2][512];
  __shared__ float sb1[512];
  __shared__ float sw2[512][4];
  for (int j = threadIdx.x; j < 512; j += 256){
    sw1[0][j] = w1[j]; sw1[1][j] = w1[512 + j]; sb1[j] = b1[j];
    for (int h = 0; h < 4; ++h) sw2[j][h] = w2[j*4 + h];
  }
  __syncthreads();
  int idx = blockIdx.x*256 + threadIdx.x;
  int r = idx >> 2, hh = idx & 3;
  if (r < T){
    float t0 = tab[2*r], t1 = tab[2*r + 1];
    float acc = 0.f;
    for (int j = 0; j < 512; ++j){
      float hj = fmaxf(fmaf(t0, sw1[0][j], fmaf(t1, sw1[1][j], sb1[j])), 0.f);
      acc = fmaf(hj, sw2[j][hh], acc);
    }
    bt[r*4 + hh] = acc;
  }
}

__global__ void bias_gather(const float* __restrict__ btw, const float* __restrict__ bts1,
                            const float* __restrict__ bts2,
                            const int* __restrict__ idxw, const int* __restrict__ idxa2w,
                            const int* __restrict__ idxw2a,
                            float* __restrict__ bw, float* __restrict__ bs1, float* __restrict__ bs2){
  int id = blockIdx.x*256 + threadIdx.x;     // 3 * 262144
  int which = id >> 18;
  int rem = id & 262143;
  int h = rem >> 16, e = rem & 65535;
  const float* bt; const int* ix; float* dst;
  if (which == 0){ bt = btw;  ix = idxw;   dst = bw;  }
  else if (which == 1){ bt = bts1; ix = idxa2w; dst = bs1; }
  else { bt = bts2; ix = idxw2a; dst = bs2; }
  float v = bt[ix[e]*4 + h];
  dst[h*65536 + e] = 16.f / (1.f + expc(-v));
}

__global__ void avgpool(const float* __restrict__ x, float* __restrict__ pooled){
  int a = blockIdx.x, c = threadIdx.x;
  int ay = a >> 6, ax = a & 63;
  float acc = 0.f;
#pragma unroll
  for (int dy = 0; dy < 4; ++dy)
#pragma unroll
    for (int dx = 0; dx < 4; ++dx)
      acc += x[(size_t)((ay*4 + dy)*256 + ax*4 + dx)*256 + c];
  pooled[(size_t)a*256 + c] = acc * 0.0625f;
}

// ---------------- GEMM: C[M,N](bf16) = A[M,K](f32) @ Bt[N,K](bf16)^T + bias(f32) ----------------
__launch_bounds__(256, 2)
__global__ void gemm_bt(const float* __restrict__ A, const u16* __restrict__ Bt,
                        const float* __restrict__ bias, u16* __restrict__ C,
                        int M, int N, int K){
  __shared__ __align__(16) u16 lsA[4096];   // [quad][128 rows][8]
  __shared__ __align__(16) u16 lsB[4096];
  const int tid = threadIdx.x, lane = tid & 63, wv = tid >> 6;
  const int lane15 = lane & 15, quad = lane >> 4;
  const int wr = wv >> 1, wc = wv & 1;
  const int m0 = blockIdx.x * 128, n0 = blockIdx.y * 128;
  floatx4 acc[4][4] = {};
  for (int k0 = 0; k0 < K; k0 += 32){
    uintx4 ra[2], rb[2];
#pragma unroll
    for (int c = 0; c < 2; ++c){
      int f = c*256 + tid, row = f & 127, q = f >> 7;
      ra[c] = ld8f_bf(A + (size_t)(m0 + row)*K + k0 + q*8);
      rb[c] = *(const uintx4*)(Bt + (size_t)(n0 + row)*K + k0 + q*8);
    }
#pragma unroll
    for (int c = 0; c < 2; ++c){
      int f = c*256 + tid;
      *(uintx4*)(lsA + f*8) = ra[c];
      *(uintx4*)(lsB + f*8) = rb[c];
    }
    __syncthreads();
    short8 a[4], b[4];
#pragma unroll
    for (int i = 0; i < 4; ++i)
      a[i] = *(const short8*)(lsA + quad*1024 + (wr*64 + i*16 + lane15)*8);
#pragma unroll
    for (int j = 0; j < 4; ++j)
      b[j] = *(const short8*)(lsB + quad*1024 + (wc*64 + j*16 + lane15)*8);
#pragma unroll
    for (int i = 0; i < 4; ++i)
#pragma unroll
      for (int j = 0; j < 4; ++j)
        acc[i][j] = __builtin_amdgcn_mfma_f32_16x16x32_bf16(a[i], b[j], acc[i][j], 0, 0, 0);
    __syncthreads();
  }
#pragma unroll
  for (int j = 0; j < 4; ++j){
    int col = n0 + wc*64 + j*16 + lane15;
    float bz = bias[col];
#pragma unroll
    for (int i = 0; i < 4; ++i){
      int rowb = m0 + wr*64 + i*16 + quad*4;
#pragma unroll
      for (int r = 0; r < 4; ++r)
        C[(size_t)(rowb + r)*N + col] = f2bf(acc[i][j][r] + bz);
    }
  }
}

// ---------------- in-place proj GEMM: AC[M,256](f32) <- AC @ Bt^T + bias ----------------
// one block per 128-row slab covering ALL 256 cols: each block reads only its own
// rows (proj output row depends only on same input row), reads complete before the
// epilogue writes -> in-place safe.
__launch_bounds__(256, 2)
__global__ void gemm_proj_inplace(float* __restrict__ AC, const u16* __restrict__ Bt,
                                  const float* __restrict__ bias){
  __shared__ __align__(16) u16 lsA[4096];   // [quad][128][8]
  __shared__ __align__(16) u16 lsB[8192];   // [quad][256][8]
  const int tid = threadIdx.x, lane = tid & 63, wv = tid >> 6;
  const int lane15 = lane & 15, quad = lane >> 4;
  const int wr = wv >> 1, wc = wv & 1;     // wave = 64 rows x 128 cols
  const int m0 = blockIdx.x * 128;
  floatx4 acc[4][8] = {};
  for (int k0 = 0; k0 < 256; k0 += 32){
    uintx4 ra[2], rb[4];
#pragma unroll
    for (int c = 0; c < 2; ++c){
      int f = c*256 + tid, row = f & 127, q = f >> 7;
      ra[c] = ld8f_bf(AC + (size_t)(m0 + row)*256 + k0 + q*8);
    }
#pragma unroll
    for (int c = 0; c < 4; ++c){
      int f = c*256 + tid, row = f & 255, q = f >> 8;
      rb[c] = *(const uintx4*)(Bt + (size_t)row*256 + k0 + q*8);
    }
#pragma unroll
    for (int c = 0; c < 2; ++c){ int f = c*256 + tid; *(uintx4*)(lsA + f*8) = ra[c]; }
#pragma unroll
    for (int c = 0; c < 4; ++c){ int f = c*256 + tid; *(uintx4*)(lsB + f*8) = rb[c]; }
    __syncthreads();
    short8 a[4], b[8];
#pragma unroll
    for (int i = 0; i < 4; ++i)
      a[i] = *(const short8*)(lsA + quad*1024 + (wr*64 + i*16 + lane15)*8);
#pragma unroll
    for (int j = 0; j < 8; ++j)
      b[j] = *(const short8*)(lsB + quad*2048 + (wc*128 + j*16 + lane15)*8);
#pragma unroll
    for (int i = 0; i < 4; ++i)
#pragma unroll
      for (int j = 0; j < 8; ++j)
        acc[i][j] = __builtin_amdgcn_mfma_f32_16x16x32_bf16(a[i], b[j], acc[i][j], 0, 0, 0);
    __syncthreads();
  }
#pragma unroll
  for (int j = 0; j < 8; ++j){
    int col = wc*128 + j*16 + lane15;
    float bz = bias[col];
#pragma unroll
    for (int i = 0; i < 4; ++i){
      int rowb = m0 + wr*64 + i*16 + quad*4;
#pragma unroll
      for (int r = 0; r < 4; ++r)
        AC[(size_t)(rowb + r)*256 + col] = acc[i][j][r] + bz;
    }
  }
}

// ---------------- window attention ----------------
// qkvh: 32768 x 384 bf16 (rows r0..r0+127 of the image), grid (128 windows, 4 heads)
__launch_bounds__(256, 2)
__global__ void win_attn(const u16* __restrict__ qkvh, const float* __restrict__ lsw,
                         const float* __restrict__ biasw, float* __restrict__ outm, int r0){
  __shared__ __align__(16) u16 sm[32768];   // 64 KB
  const int tid = threadIdx.x, lane = tid & 63, wv = tid >> 6;
  const int lane15 = lane & 15, quad = lane >> 4;
  const int h = blockIdx.y;
  const int wyl = blockIdx.x >> 4, wx = blockIdx.x & 15;

  { // load + normalize q,k ; v transposed
    int t = tid;
    int pyl = wyl*16 + (t >> 4), px = wx*16 + (t & 15);
    const u16* base = qkvh + (size_t)(pyl*256 + px)*384 + h*32;
    float v[32];
    load32(base, v);        norm_store(sm,        v, t, 2048);   // Q [4][256][8]
    load32(base + 128, v);  norm_store(sm + 8192, v, t, 2048);   // K
    load32(base + 256, v);
    {
      u16* VT = sm + 16384;                                      // [32][32][8]
      int kq = t >> 3, e = t & 7;
#pragma unroll
      for (int d = 0; d < 32; ++d) VT[kq*256 + d*8 + e] = f2bf(v[d]);
    }
  }
  __syncthreads();
  short8 qf[4];
#pragma unroll
  for (int i = 0; i < 4; ++i)
    qf[i] = *(const short8*)(sm + quad*2048 + (wv*64 + i*16 + lane15)*8);
  __syncthreads();   // Q reads done before P overwrites

  float scale = __expf(fminf(lsw[h], 4.6051702f));
  float off = fminf(scale + 16.f, 80.f);
  u16* Pw = sm + ((wv < 2) ? wv*4096 : 24576 + (wv - 2)*4096);  // [8][64][8] per wave
  const u16* Ksm = sm + 8192;
  const u16* VT = sm + 16384;
  const float* bptr = biasw + ((size_t)h << 16);
  const floatx4 zf4 = {0.f, 0.f, 0.f, 0.f};

  floatx4 accO[4][2] = {};
  float lsum[4][4] = {};

  for (int kc = 0; kc < 4; ++kc){
    short8 kf[4];
#pragma unroll
    for (int j = 0; j < 4; ++j)
      kf[j] = *(const short8*)(Ksm + quad*2048 + (kc*64 + j*16 + lane15)*8);
#pragma unroll
    for (int i = 0; i < 4; ++i){
      int rowb = wv*64 + i*16 + quad*4;
#pragma unroll
      for (int j = 0; j < 4; ++j){
        floatx4 s = __builtin_amdgcn_mfma_f32_16x16x32_bf16(qf[i], kf[j], zf4, 0, 0, 0);
        int kcol = j*16 + lane15;
        int keyg = kc*64 + kcol;
#pragma unroll
        for (int r = 0; r < 4; ++r){
          float b = bptr[(rowb + r)*256 + keyg];
          float p = expc(fmaf(s[r], scale, b) - off);
          lsum[i][r] += p;
          Pw[(kcol >> 3)*512 + (i*16 + quad*4 + r)*8 + (kcol & 7)] = f2bf(p);
        }
      }
    }
    asm volatile("s_waitcnt lgkmcnt(0)" ::: "memory");
#pragma unroll
    for (int i = 0; i < 4; ++i){
#pragma unroll
      for (int ks = 0; ks < 2; ++ks){
        short8 pf = *(const short8*)(Pw + (ks*4 + quad)*512 + (i*16 + lane15)*8);
#pragma unroll
        for (int j2 = 0; j2 < 2; ++j2){
          short8 vf = *(const short8*)(VT + (kc*8 + ks*4 + quad)*256 + (j2*16 + lane15)*8);
          accO[i][j2] = __builtin_amdgcn_mfma_f32_16x16x32_bf16(pf, vf, accO[i][j2], 0, 0, 0);
        }
      }
    }
  }
#pragma unroll
  for (int i = 0; i < 4; ++i){
    float linv[4];
#pragma unroll
    for (int r = 0; r < 4; ++r) linv[r] = 1.f / rsum16(lsum[i][r]);
#pragma unroll
    for (int j2 = 0; j2 < 2; ++j2)
#pragma unroll
      for (int r = 0; r < 4; ++r){
        int tok = wv*64 + i*16 + quad*4 + r;
        int py = r0 + wyl*16 + (tok >> 4), px = wx*16 + (tok & 15);
        outm[(size_t)(py*256 + px)*256 + h*32 + j2*16 + lane15] = accO[i][j2][r] * linv[r];
      }
  }
}

// ---------------- stripe (anchor) attention ----------------
// qkvh: 32768 x 384 bf16 (rows r0..r0+127), grid (32 stripes, 4 heads)
__launch_bounds__(256, 2)
__global__ void stripe_attn(const u16* __restrict__ qkvh, const u16* __restrict__ anchor,
                            const float* __restrict__ ls1, const float* __restrict__ ls2,
                            const float* __restrict__ bias1, const float* __restrict__ bias2,
                            float* __restrict__ outm, int r0){
  __shared__ __align__(16) u16 sm[28672];
  const int tid = threadIdx.x, lane = tid & 63, wv = tid >> 6;
  const int lane15 = lane & 15, quad = lane >> 4;
  const int h = blockIdx.y;
  const int syl = blockIdx.x >> 3, sx = blockIdx.x & 7;

  u16* ANC = sm;                         // [4][64][8]
  u16* XMT = sm + 2048;                  // [8][32][8]
  u16* KC  = sm + 4096;                  // [4][128][8]   (phase B)
  u16* VT  = sm + 8192;                  // [16][32][8]   (phase B)
  u16* P1  = sm + 12288 + wv*2048;       // [16][16][8]   (phase B)
  u16* P2  = sm + 4096  + wv*4096;       // [8][64][8]    (phase D, aliases KC/VT/P1)
  u16* QW  = sm + 20480 + wv*2048;       // [4][64][8]    (phase D)

  if (tid < 64){
    int t = tid;
    int ay = (r0 >> 2) + syl*8 + (t >> 3), ax = sx*8 + (t & 7);
    const u16* ab = anchor + (size_t)(ay*64 + ax)*128 + h*32;
    float v[32]; load32(ab, v);
    norm_store(ANC, v, t, 512);
  }
  __syncthreads();

  float scale1 = __expf(fminf(ls1[h], 4.6051702f));
  float off1 = fminf(scale1 + 16.f, 80.f);
  float scale2 = __expf(fminf(ls2[h], 4.6051702f));
  float off2 = fminf(scale2 + 16.f, 80.f);
  const float* b1p = bias1 + ((size_t)h << 16);
  const float* b2p = bias2 + ((size_t)h << 16);
  const floatx4 zf4 = {0.f, 0.f, 0.f, 0.f};

  floatx4 accO1[2] = {};
  float l1[4] = {};

  for (int kc = 0; kc < 8; ++kc){
    { // stage k (threads 0-127) and v (threads 128-255)
      int t = tid;
      if (t < 128){
        int tok = kc*128 + t;
        int pyl = syl*32 + (tok >> 5), px = sx*32 + (tok & 31);
        const u16* kb = qkvh + (size_t)(pyl*256 + px)*384 + 128 + h*32;
        float v[32]; load32(kb, v);
        norm_store(KC, v, t, 1024);
      } else {
        int t2 = t - 128;
        int tok = kc*128 + t2;
        int pyl = syl*32 + (tok >> 5), px = sx*32 + (tok & 31);
        const u16* vb = qkvh + (size_t)(pyl*256 + px)*384 + 256 + h*32;
        float v[32]; load32(vb, v);
        int kq = t2 >> 3, e = t2 & 7;
#pragma unroll
        for (int d = 0; d < 32; ++d) VT[kq*256 + d*8 + e] = f2bf(v[d]);
      }
    }
    __syncthreads();
    short8 a0 = *(const short8*)(ANC + quad*512 + (wv*16 + lane15)*8);
#pragma unroll
    for (int j = 0; j < 8; ++j){
      short8 kf = *(const short8*)(KC + quad*1024 + (j*16 + lane15)*8);
      floatx4 sv = __builtin_amdgcn_mfma_f32_16x16x32_bf16(a0, kf, zf4, 0, 0, 0);
      int kcol = j*16 + lane15;
      int keyg = kc*128 + kcol;
#pragma unroll
      for (int r = 0; r < 4; ++r){
        int arow = wv*16 + quad*4 + r;
        float b = b1p[(size_t)arow*1024 + keyg];
        float p = expc(fmaf(sv[r], scale1, b) - off1);
        l1[r] += p;
        P1[(kcol >> 3)*128 + (quad*4 + r)*8 + (kcol & 7)] = f2bf(p);
      }
    }
    asm volatile("s_waitcnt lgkmcnt(0)" ::: "memory");
#pragma unroll
    for (int ks = 0; ks < 4; ++ks){
      short8 pf = *(const short8*)(P1 + (ks*4 + quad)*128 + lane15*8);
#pragma unroll
      for (int j2 = 0; j2 < 2; ++j2){
        short8 vf = *(const short8*)(VT + (ks*4 + quad)*256 + (j2*16 + lane15)*8);
        accO1[j2] = __builtin_amdgcn_mfma_f32_16x16x32_bf16(pf, vf, accO1[j2], 0, 0, 0);
      }
    }
    __syncthreads();
  }
  { // xm -> XMT (transposed, bf16)
    float linv[4];
#pragma unroll
    for (int r = 0; r < 4; ++r) linv[r] = 1.f / rsum16(l1[r]);
#pragma unroll
    for (int j2 = 0; j2 < 2; ++j2)
#pragma unroll
      for (int r = 0; r < 4; ++r){
        int row = wv*16 + quad*4 + r;
        int d = j2*16 + lane15;
        XMT[(row >> 3)*256 + d*8 + (row & 7)] = f2bf(accO1[j2][r] * linv[r]);
      }
  }
  __syncthreads();
  // phase D: xs = softmax(q@anc^T)@xm
  for (int qc = 0; qc < 4; ++qc){
    int t0 = wv*256 + qc*64;
    {
      int tok = t0 + lane;
      int pyl = syl*32 + (tok >> 5), px = sx*32 + (tok & 31);
      const u16* qb = qkvh + (size_t)(pyl*256 + px)*384 + h*32;
      float v[32]; load32(qb, v);
      norm_store(QW, v, lane, 512);
    }
    asm volatile("s_waitcnt lgkmcnt(0)" ::: "memory");
    short8 qf2[4];
#pragma unroll
    for (int i = 0; i < 4; ++i)
      qf2[i] = *(const short8*)(QW + quad*512 + (i*16 + lane15)*8);
    float l2[4][4] = {};
#pragma unroll
    for (int j = 0; j < 4; ++j){
      short8 bfr = *(const short8*)(ANC + quad*512 + (j*16 + lane15)*8);
#pragma unroll
      for (int i = 0; i < 4; ++i){
        floatx4 sv = __builtin_amdgcn_mfma_f32_16x16x32_bf16(qf2[i], bfr, zf4, 0, 0, 0);
        int col = j*16 + lane15;
#pragma unroll
        for (int r = 0; r < 4; ++r){
          int qrow = t0 + i*16 + quad*4 + r;
          float b = b2p[(size_t)qrow*64 + col];
          float p = expc(fmaf(sv[r], scale2, b) - off2);
          l2[i][r] += p;
          P2[(col >> 3)*512 + (i*16 + quad*4 + r)*8 + (col & 7)] = f2bf(p);
        }
      }
    }
    asm volatile("s_waitcnt lgkmcnt(0)" ::: "memory");
    floatx4 accO2[4][2] = {};
#pragma unroll
    for (int i = 0; i < 4; ++i)
#pragma unroll
      for (int ks = 0; ks < 2; ++ks){
        short8 pf = *(const short8*)(P2 + (ks*4 + quad)*512 + (i*16 + lane15)*8);
#pragma unroll
        for (int j2 = 0; j2 < 2; ++j2){
          short8 xf = *(const short8*)(XMT + (ks*4 + quad)*256 + (j2*16 + lane15)*8);
          accO2[i][j2] = __builtin_amdgcn_mfma_f32_16x16x32_bf16(pf, xf, accO2[i][j2], 0, 0, 0);
        }
      }
#pragma unroll
    for (int i = 0; i < 4; ++i){
      float linv[4];
#pragma unroll
      for (int r = 0; r < 4; ++r) linv[r] = 1.f / rsum16(l2[i][r]);
#pragma unroll
      for (int j2 = 0; j2 < 2; ++j2)
#pragma unroll
        for (int r = 0; r < 4; ++r){
          int tok = t0 + i*16 + quad*4 + r;
          int py = r0 + syl*32 + (tok >> 5), px = sx*32 + (tok & 31);
          outm[(size_t)(py*256 + px)*256 + 128 + h*32 + j2*16 + lane15] = accO2[i][j2][r] * linv[r];
        }
    }
  }
}

// ---------------- launch ----------------
extern "C" void kernel_launch(void* const* d_in, const int* in_sizes, int n_in,
                              void* d_out, int out_size, void* d_ws, size_t ws_size,
                              hipStream_t stream) {
  (void)in_sizes; (void)n_in; (void)out_size; (void)ws_size;
  const float* x        = (const float*)d_in[0];
  const float* qkv_w    = (const float*)d_in[1];
  const float* qkv_b    = (const float*)d_in[2];
  const float* anchor_w = (const float*)d_in[3];
  const float* anchor_b = (const float*)d_in[4];
  const float* ls_w     = (const float*)d_in[5];
  const float* w1_w     = (const float*)d_in[6];
  const float* b1_w     = (const float*)d_in[7];
  const float* w2_w     = (const float*)d_in[8];
  const float* ls_s1    = (const float*)d_in[9];
  const float* w1_s1    = (const float*)d_in[10];
  const float* b1_s1    = (const float*)d_in[11];
  const float* w2_s1    = (const float*)d_in[12];
  const float* ls_s2    = (const float*)d_in[13];
  const float* w1_s2    = (const float*)d_in[14];
  const float* b1_s2    = (const float*)d_in[15];
  const float* w2_s2    = (const float*)d_in[16];
  const float* proj_w   = (const float*)d_in[17];
  const float* proj_b   = (const float*)d_in[18];
  const float* table_w  = (const float*)d_in[19];
  const float* table_s  = (const float*)d_in[20];
  const int* index_w   = (const int*)d_in[21];
  const int* index_a2w = (const int*)d_in[22];
  const int* index_w2a = (const int*)d_in[23];

  // ---- workspace layout (28.6 MB peak) ----
  char* ws = (char*)d_ws;
  u16*   qkvh   = (u16*)(ws + 0);                  // 32768*384 bf16 = 25165824 B (reused 4x)
  float* pooled = (float*)(ws + 0);                // 4096*256 f32 = 4 MB; dead before qkvh written
  u16*   anch   = (u16*)(ws + 25165824);           // 4096*128 bf16 = 1048576 B
  u16*   qkvt   = (u16*)(ws + 26214400);           // 768*256 bf16
  u16*   anct   = (u16*)(ws + 26607616);           // 128*256 bf16
  u16*   projt  = (u16*)(ws + 26673152);           // 256*256 bf16
  float* btw    = (float*)(ws + 26804224);         // 961*4 f32
  float* bts1   = (float*)(ws + 26820608);         // 1521*4 f32
  float* bts2   = (float*)(ws + 26845184);         // 1521*4 f32
  float* biasw  = (float*)(ws + 26869760);         // 4*256*256 f32
  float* bias1  = (float*)(ws + 27918336);         // 4*64*1024 f32
  float* bias2  = (float*)(ws + 28966912);         // 4*1024*64 f32  (end 30015488)

  float* merged = (float*)d_out;                   // f32 scratch, then final output (in-place proj)

  transpose_w<<<1152, 256, 0, stream>>>(qkv_w, anchor_w, proj_w, qkvt, anct, projt);
  cpb_mlp<<<dim3(24, 3), 256, 0, stream>>>(table_w, table_s,
                                           w1_w, b1_w, w2_w,
                                           w1_s1, b1_s1, w2_s1,
                                           w1_s2, b1_s2, w2_s2,
                                           btw, bts1, bts2);
  bias_gather<<<3072, 256, 0, stream>>>(btw, bts1, bts2, index_w, index_a2w, index_w2a,
                                        biasw, bias1, bias2);
  avgpool<<<4096, 256, 0, stream>>>(x, pooled);
  gemm_bt<<<dim3(32, 1), 256, 0, stream>>>(pooled, anct, anchor_b, anch, 4096, 128, 256);

  for (int half = 0; half < 2; ++half){
    const float* xh = x + (size_t)half*32768*256;
    int r0 = half*128;
    // window branch, qkv channels [0,384)
    gemm_bt<<<dim3(256, 3), 256, 0, stream>>>(xh, qkvt, qkv_b, qkvh, 32768, 384, 256);
    win_attn<<<dim3(128, 4), 256, 0, stream>>>(qkvh, ls_w, biasw, merged, r0);
    // stripe branch, qkv channels [384,768)
    gemm_bt<<<dim3(256, 3), 256, 0, stream>>>(xh, qkvt + 384*256, qkv_b + 384, qkvh, 32768, 384, 256);
    stripe_attn<<<dim3(32, 4), 256, 0, stream>>>(qkvh, anch, ls_s1, ls_s2, bias1, bias2, merged, r0);
  }

  // output projection, in place on f32 d_out
  gemm_proj_inplace<<<dim3(512), 256, 0, stream>>>(merged, projt, proj_b);
}

// Round 5
// 404.059 us; speedup vs baseline: 1.3225x; 1.3225x over previous
//
#include <hip/hip_runtime.h>
#include <cstdint>
#include <cstddef>

typedef unsigned short u16;
typedef __attribute__((ext_vector_type(8))) short short8;
typedef __attribute__((ext_vector_type(4))) float floatx4;
typedef __attribute__((ext_vector_type(4))) unsigned int uintx4;
typedef __attribute__((ext_vector_type(2))) unsigned int uintx2;

__device__ __forceinline__ float bf2f(u16 u){
  union { unsigned int i; float f; } v; v.i = ((unsigned int)u) << 16; return v.f;
}
__device__ __forceinline__ u16 f2bf(float f){
  union { float ff; unsigned int i; } v; v.ff = f;
  return (u16)((v.i + 0x7fffu + ((v.i >> 16) & 1u)) >> 16);
}
__device__ __forceinline__ unsigned int pk2(float a, float b){
  return (unsigned int)f2bf(a) | ((unsigned int)f2bf(b) << 16);
}
// read 32 bf16 (internal buffers) -> 32 floats
__device__ __forceinline__ void load32(const u16* p, float* v){
  const uintx4* p4 = (const uintx4*)p;
#pragma unroll
  for (int c = 0; c < 4; ++c){
    uintx4 u = p4[c];
    v[c*8+0] = bf2f((u16)(u.x & 0xffffu)); v[c*8+1] = bf2f((u16)(u.x >> 16));
    v[c*8+2] = bf2f((u16)(u.y & 0xffffu)); v[c*8+3] = bf2f((u16)(u.y >> 16));
    v[c*8+4] = bf2f((u16)(u.z & 0xffffu)); v[c*8+5] = bf2f((u16)(u.z >> 16));
    v[c*8+6] = bf2f((u16)(u.w & 0xffffu)); v[c*8+7] = bf2f((u16)(u.w >> 16));
  }
}
// L2-normalize a 32-vector, store bf16 in k-outer layout [4][R][8]
__device__ __forceinline__ void norm_store(u16* dst, const float* v, int t, int strideU16){
  float ss = 0.f;
#pragma unroll
  for (int e = 0; e < 32; ++e) ss += v[e]*v[e];
  float inv = 1.f / fmaxf(sqrtf(ss), 1e-12f);
#pragma unroll
  for (int q = 0; q < 4; ++q){
    uintx4 u;
    u.x = pk2(v[q*8+0]*inv, v[q*8+1]*inv);
    u.y = pk2(v[q*8+2]*inv, v[q*8+3]*inv);
    u.z = pk2(v[q*8+4]*inv, v[q*8+5]*inv);
    u.w = pk2(v[q*8+6]*inv, v[q*8+7]*inv);
    *(uintx4*)(dst + q*strideU16 + t*8) = u;
  }
}
__device__ __forceinline__ float expc(float a){   // clamped exp: never inf
  return __expf(fminf(a, 30.f));
}
// load 8 fp32 from g, convert to 8 bf16 packed in a uintx4
__device__ __forceinline__ uintx4 ld8f_bf(const float* g){
  floatx4 u0 = *(const floatx4*)g;
  floatx4 u1 = *(const floatx4*)(g + 4);
  uintx4 w;
  w.x = pk2(u0.x, u0.y); w.y = pk2(u0.z, u0.w);
  w.z = pk2(u1.x, u1.y); w.w = pk2(u1.z, u1.w);
  return w;
}
__device__ __forceinline__ float redq(float v){   // sum across quads (lanes ^16, ^32)
  v += __shfl_xor(v, 16); v += __shfl_xor(v, 32);
  return v;
}

// ---------------- prep kernels ----------------
__global__ void transpose_w(const float* __restrict__ qkv_w, const float* __restrict__ anchor_w,
                            const float* __restrict__ proj_w,
                            u16* __restrict__ qkvt, u16* __restrict__ anct, u16* __restrict__ projt){
  int id = blockIdx.x*256 + threadIdx.x;
  if (id < 196608){ int k = id / 768, n = id % 768; qkvt[n*256 + k] = f2bf(qkv_w[id]); }
  else if (id < 229376){ int r = id - 196608; int k = r / 128, n = r % 128; anct[n*256 + k] = f2bf(anchor_w[r]); }
  else { int r = id - 229376; int k = r >> 8, n = r & 255; projt[n*256 + k] = f2bf(proj_w[r]); }
}

__global__ void cpb_mlp(const float* __restrict__ tw, const float* __restrict__ ts,
                        const float* __restrict__ w1w, const float* __restrict__ b1w, const float* __restrict__ w2w,
                        const float* __restrict__ w1s1, const float* __restrict__ b1s1, const float* __restrict__ w2s1,
                        const float* __restrict__ w1s2, const float* __restrict__ b1s2, const float* __restrict__ w2s2,
                        float* __restrict__ btw, float* __restrict__ bts1, float* __restrict__ bts2){
  int tag = blockIdx.y;
  const float *tab, *w1, *b1, *w2; float* bt; int T;
  if (tag == 0){ tab = tw; w1 = w1w;  b1 = b1w;  w2 = w2w;  bt = btw;  T = 961; }
  else if (tag == 1){ tab = ts; w1 = w1s1; b1 = b1s1; w2 = w2s1; bt = bts1; T = 1521; }
  else { tab = ts; w1 = w1s2; b1 = b1s2; w2 = w2s2; bt = bts2; T = 1521; }
  __shared__ float sw1[2][512];
  __shared__ float sb1[512];
  __shared__ float sw2[512][4];
  for (int j = threadIdx.x; j < 512; j += 256){
    sw1[0][j] = w1[j]; sw1[1][j] = w1[512 + j]; sb1[j] = b1[j];
    for (int h = 0; h < 4; ++h) sw2[j][h] = w2[j*4 + h];
  }
  __syncthreads();
  int idx = blockIdx.x*256 + threadIdx.x;
  int r = idx >> 2, hh = idx & 3;
  if (r < T){
    float t0 = tab[2*r], t1 = tab[2*r + 1];
    float acc = 0.f;
    for (int j = 0; j < 512; ++j){
      float hj = fmaxf(fmaf(t0, sw1[0][j], fmaf(t1, sw1[1][j], sb1[j])), 0.f);
      acc = fmaf(hj, sw2[j][hh], acc);
    }
    bt[r*4 + hh] = acc;
  }
}

__global__ void bias_gather(const float* __restrict__ btw, const float* __restrict__ bts1,
                            const float* __restrict__ bts2,
                            const int* __restrict__ idxw, const int* __restrict__ idxa2w,
                            const int* __restrict__ idxw2a,
                            float* __restrict__ bw, float* __restrict__ bs1, float* __restrict__ bs2){
  int id = blockIdx.x*256 + threadIdx.x;     // 3 * 262144
  int which = id >> 18;
  int rem = id & 262143;
  int h = rem >> 16, e = rem & 65535;
  const float* bt; const int* ix; float* dst;
  if (which == 0){ bt = btw;  ix = idxw;   dst = bw;  }
  else if (which == 1){ bt = bts1; ix = idxa2w; dst = bs1; }
  else { bt = bts2; ix = idxw2a; dst = bs2; }
  float v = bt[ix[e]*4 + h];
  dst[h*65536 + e] = 16.f / (1.f + expc(-v));
}

__global__ void avgpool(const float* __restrict__ x, float* __restrict__ pooled){
  int a = blockIdx.x, c = threadIdx.x;
  int ay = a >> 6, ax = a & 63;
  float acc = 0.f;
#pragma unroll
  for (int dy = 0; dy < 4; ++dy)
#pragma unroll
    for (int dx = 0; dx < 4; ++dx)
      acc += x[(size_t)((ay*4 + dy)*256 + ax*4 + dx)*256 + c];
  pooled[(size_t)a*256 + c] = acc * 0.0625f;
}

// ---------------- GEMM: C[M,N](bf16) = A[M,K](f32) @ Bt[N,K](bf16)^T + bias(f32) ----------------
__launch_bounds__(256, 2)
__global__ void gemm_bt(const float* __restrict__ A, const u16* __restrict__ Bt,
                        const float* __restrict__ bias, u16* __restrict__ C,
                        int M, int N, int K){
  __shared__ __align__(16) u16 lsA[4096];   // [quad][128 rows][8]
  __shared__ __align__(16) u16 lsB[4096];
  const int tid = threadIdx.x, lane = tid & 63, wv = tid >> 6;
  const int lane15 = lane & 15, quad = lane >> 4;
  const int wr = wv >> 1, wc = wv & 1;
  const int m0 = blockIdx.x * 128, n0 = blockIdx.y * 128;
  floatx4 acc[4][4] = {};
  for (int k0 = 0; k0 < K; k0 += 32){
    uintx4 ra[2], rb[2];
#pragma unroll
    for (int c = 0; c < 2; ++c){
      int f = c*256 + tid, row = f & 127, q = f >> 7;
      ra[c] = ld8f_bf(A + (size_t)(m0 + row)*K + k0 + q*8);
      rb[c] = *(const uintx4*)(Bt + (size_t)(n0 + row)*K + k0 + q*8);
    }
#pragma unroll
    for (int c = 0; c < 2; ++c){
      int f = c*256 + tid;
      *(uintx4*)(lsA + f*8) = ra[c];
      *(uintx4*)(lsB + f*8) = rb[c];
    }
    __syncthreads();
    short8 a[4], b[4];
#pragma unroll
    for (int i = 0; i < 4; ++i)
      a[i] = *(const short8*)(lsA + quad*1024 + (wr*64 + i*16 + lane15)*8);
#pragma unroll
    for (int j = 0; j < 4; ++j)
      b[j] = *(const short8*)(lsB + quad*1024 + (wc*64 + j*16 + lane15)*8);
#pragma unroll
    for (int i = 0; i < 4; ++i)
#pragma unroll
      for (int j = 0; j < 4; ++j)
        acc[i][j] = __builtin_amdgcn_mfma_f32_16x16x32_bf16(a[i], b[j], acc[i][j], 0, 0, 0);
    __syncthreads();
  }
#pragma unroll
  for (int j = 0; j < 4; ++j){
    int col = n0 + wc*64 + j*16 + lane15;
    float bz = bias[col];
#pragma unroll
    for (int i = 0; i < 4; ++i){
      int rowb = m0 + wr*64 + i*16 + quad*4;
#pragma unroll
      for (int r = 0; r < 4; ++r)
        C[(size_t)(rowb + r)*N + col] = f2bf(acc[i][j][r] + bz);
    }
  }
}

// ---------------- in-place proj GEMM: AC[M,256](f32) <- AC @ Bt^T + bias ----------------
__launch_bounds__(256, 2)
__global__ void gemm_proj_inplace(float* __restrict__ AC, const u16* __restrict__ Bt,
                                  const float* __restrict__ bias){
  __shared__ __align__(16) u16 lsA[4096];   // [quad][128][8]
  __shared__ __align__(16) u16 lsB[8192];   // [quad][256][8]
  const int tid = threadIdx.x, lane = tid & 63, wv = tid >> 6;
  const int lane15 = lane & 15, quad = lane >> 4;
  const int wr = wv >> 1, wc = wv & 1;     // wave = 64 rows x 128 cols
  const int m0 = blockIdx.x * 128;
  floatx4 acc[4][8] = {};
  for (int k0 = 0; k0 < 256; k0 += 32){
    uintx4 ra[2], rb[4];
#pragma unroll
    for (int c = 0; c < 2; ++c){
      int f = c*256 + tid, row = f & 127, q = f >> 7;
      ra[c] = ld8f_bf(AC + (size_t)(m0 + row)*256 + k0 + q*8);
    }
#pragma unroll
    for (int c = 0; c < 4; ++c){
      int f = c*256 + tid, row = f & 255, q = f >> 8;
      rb[c] = *(const uintx4*)(Bt + (size_t)row*256 + k0 + q*8);
    }
#pragma unroll
    for (int c = 0; c < 2; ++c){ int f = c*256 + tid; *(uintx4*)(lsA + f*8) = ra[c]; }
#pragma unroll
    for (int c = 0; c < 4; ++c){ int f = c*256 + tid; *(uintx4*)(lsB + f*8) = rb[c]; }
    __syncthreads();
    short8 a[4], b[8];
#pragma unroll
    for (int i = 0; i < 4; ++i)
      a[i] = *(const short8*)(lsA + quad*1024 + (wr*64 + i*16 + lane15)*8);
#pragma unroll
    for (int j = 0; j < 8; ++j)
      b[j] = *(const short8*)(lsB + quad*2048 + (wc*128 + j*16 + lane15)*8);
#pragma unroll
    for (int i = 0; i < 4; ++i)
#pragma unroll
      for (int j = 0; j < 8; ++j)
        acc[i][j] = __builtin_amdgcn_mfma_f32_16x16x32_bf16(a[i], b[j], acc[i][j], 0, 0, 0);
    __syncthreads();
  }
#pragma unroll
  for (int j = 0; j < 8; ++j){
    int col = wc*128 + j*16 + lane15;
    float bz = bias[col];
#pragma unroll
    for (int i = 0; i < 4; ++i){
      int rowb = m0 + wr*64 + i*16 + quad*4;
#pragma unroll
      for (int r = 0; r < 4; ++r)
        AC[(size_t)(rowb + r)*256 + col] = acc[i][j][r] + bz;
    }
  }
}

// ---------------- window attention (S^T formulation) ----------------
// qkvh: 32768 x 384 bf16 (image rows r0..r0+127), grid (128 windows, 4 heads)
__launch_bounds__(256, 3)
__global__ void win_attn(const u16* __restrict__ qkvh, const float* __restrict__ lsw,
                         const float* __restrict__ biasw, float* __restrict__ outm, int r0){
  __shared__ __align__(16) u16 sm[24576];   // 48 KB: K[0,8192) Q[8192,16384)->P  VT[16384,24576)
  const int tid = threadIdx.x, lane = tid & 63, wv = tid >> 6;
  const int lane15 = lane & 15, quad = lane >> 4;
  const int h = blockIdx.y;
  const int wyl = blockIdx.x >> 4, wx = blockIdx.x & 15;
  u16* Ks = sm;
  u16* Qs = sm + 8192;
  u16* VT = sm + 16384;
  { // stage: normalized Q,K in k-outer layout; V transposed [key-oct][d][8]
    int t = tid;
    int pyl = wyl*16 + (t >> 4), px = wx*16 + (t & 15);
    const u16* base = qkvh + (size_t)(pyl*256 + px)*384 + h*32;
    float v[32];
    load32(base, v);        norm_store(Qs, v, t, 2048);
    load32(base + 128, v);  norm_store(Ks, v, t, 2048);
    load32(base + 256, v);
    int kq = t >> 3, e = t & 7;
#pragma unroll
    for (int d = 0; d < 32; ++d) VT[kq*256 + d*8 + e] = f2bf(v[d]);
  }
  __syncthreads();
  short8 qf[4];                 // wave owns queries wv*64 .. +63 (B-operand)
#pragma unroll
  for (int j = 0; j < 4; ++j)
    qf[j] = *(const short8*)(Qs + quad*2048 + (wv*64 + j*16 + lane15)*8);
  __syncthreads();              // all Q reads done before P overwrites

  float scale = __expf(fminf(lsw[h], 4.6051702f));
  float off = fminf(scale + 16.f, 80.f);
  const float* bptr = biasw + ((size_t)h << 16);
  u16* Pw = Qs + wv*2048;       // per-wave P^T: [4 key-octs][64 queries][8]
  const floatx4 zf4 = {0.f, 0.f, 0.f, 0.f};
  floatx4 accO[2][4] = {};      // O^T: [d-tile][query-tile]
  float lsum[4] = {};

  for (int kc = 0; kc < 8; ++kc){      // 32 keys per chunk
    floatx4 bia[2][4];
#pragma unroll
    for (int i = 0; i < 2; ++i)
#pragma unroll
      for (int j = 0; j < 4; ++j)
        bia[i][j] = *(const floatx4*)(bptr + (size_t)(wv*64 + j*16 + lane15)*256 + kc*32 + i*16 + quad*4);
    short8 kf[2];
#pragma unroll
    for (int i = 0; i < 2; ++i)
      kf[i] = *(const short8*)(Ks + quad*2048 + (kc*32 + i*16 + lane15)*8);
#pragma unroll
    for (int i = 0; i < 2; ++i)
#pragma unroll
      for (int j = 0; j < 4; ++j){
        floatx4 sv = __builtin_amdgcn_mfma_f32_16x16x32_bf16(kf[i], qf[j], zf4, 0, 0, 0);
        float p0 = expc(fmaf(sv[0], scale, bia[i][j][0]) - off);
        float p1 = expc(fmaf(sv[1], scale, bia[i][j][1]) - off);
        float p2 = expc(fmaf(sv[2], scale, bia[i][j][2]) - off);
        float p3 = expc(fmaf(sv[3], scale, bia[i][j][3]) - off);
        lsum[j] += (p0 + p1) + (p2 + p3);
        uintx2 w; w.x = pk2(p0, p1); w.y = pk2(p2, p3);
        *(uintx2*)(Pw + (i*2 + (quad>>1))*512 + (j*16 + lane15)*8 + (quad&1)*4) = w;
      }
    asm volatile("s_waitcnt lgkmcnt(0)" ::: "memory");
    short8 ptf[4], vtf[2];
#pragma unroll
    for (int j = 0; j < 4; ++j)
      ptf[j] = *(const short8*)(Pw + quad*512 + (j*16 + lane15)*8);
#pragma unroll
    for (int m = 0; m < 2; ++m)
      vtf[m] = *(const short8*)(VT + (kc*4 + quad)*256 + (m*16 + lane15)*8);
#pragma unroll
    for (int m = 0; m < 2; ++m)
#pragma unroll
      for (int j = 0; j < 4; ++j)
        accO[m][j] = __builtin_amdgcn_mfma_f32_16x16x32_bf16(vtf[m], ptf[j], accO[m][j], 0, 0, 0);
  }
  float linv[4];
#pragma unroll
  for (int j = 0; j < 4; ++j) linv[j] = 1.f / redq(lsum[j]);
#pragma unroll
  for (int m = 0; m < 2; ++m)
#pragma unroll
    for (int j = 0; j < 4; ++j){
      int tok = wv*64 + j*16 + lane15;
      int py = r0 + wyl*16 + (tok >> 4), px = wx*16 + (tok & 15);
      floatx4 o = accO[m][j] * linv[j];
      *(floatx4*)(outm + (size_t)(py*256 + px)*256 + h*32 + m*16 + quad*4) = o;
    }
}

// ---------------- stripe phase 1: xm partials (key-split) ----------------
// grid (32 stripes, 4 heads, 2 key-halves)
__launch_bounds__(256, 3)
__global__ void stripe_xm(const u16* __restrict__ qkvh, const u16* __restrict__ anchor,
                          const float* __restrict__ ls1, const float* __restrict__ bias1,
                          float* __restrict__ gl1, u16* __restrict__ gO, int r0){
  __shared__ __align__(16) u16 sm[18432];  // ANC[0,2048) KC[2048,6144) VT[6144,10240) P1T[10240,18432)
  const int tid = threadIdx.x, lane = tid & 63, wv = tid >> 6;
  const int lane15 = lane & 15, quad = lane >> 4;
  const int s = blockIdx.x, h = blockIdx.y, kb = blockIdx.z;
  const int syl = s >> 3, sx = s & 7;
  u16* ANC = sm; u16* KC = sm + 2048; u16* VT = sm + 6144; u16* P1T = sm + 10240;
  if (tid < 64){
    int ay = (r0 >> 2) + syl*8 + (tid >> 3), ax = sx*8 + (tid & 7);
    float v[32]; load32(anchor + (size_t)(ay*64 + ax)*128 + h*32, v);
    norm_store(ANC, v, tid, 512);
  }
  __syncthreads();
  short8 ancf = *(const short8*)(ANC + quad*512 + (wv*16 + lane15)*8);   // wave's 16 anchors (B-side)
  float scale1 = __expf(fminf(ls1[h], 4.6051702f));
  float off1 = fminf(scale1 + 16.f, 80.f);
  const float* b1p = bias1 + ((size_t)h << 16) + (size_t)(wv*16 + lane15)*1024;
  const floatx4 zf4 = {0.f, 0.f, 0.f, 0.f};
  floatx4 accO1[2] = {};
  float l1 = 0.f;
  for (int kc = 0; kc < 4; ++kc){
    int kkb = kb*512 + kc*128;
    { int t = tid;
      if (t < 128){
        int tok = kkb + t;
        int pyl = syl*32 + (tok >> 5), px = sx*32 + (tok & 31);
        float v[32]; load32(qkvh + (size_t)(pyl*256 + px)*384 + 128 + h*32, v);
        norm_store(KC, v, t, 1024);
      } else {
        int t2 = t - 128, tok = kkb + t2;
        int pyl = syl*32 + (tok >> 5), px = sx*32 + (tok & 31);
        float v[32]; load32(qkvh + (size_t)(pyl*256 + px)*384 + 256 + h*32, v);
        int kq = t2 >> 3, e = t2 & 7;
#pragma unroll
        for (int d = 0; d < 32; ++d) VT[kq*256 + d*8 + e] = f2bf(v[d]);
      }
    }
    __syncthreads();
    floatx4 bia[8];
#pragma unroll
    for (int i = 0; i < 8; ++i)
      bia[i] = *(const floatx4*)(b1p + kkb + i*16 + quad*4);
#pragma unroll
    for (int i = 0; i < 8; ++i){
      short8 kf = *(const short8*)(KC + quad*1024 + (i*16 + lane15)*8);
      floatx4 sv = __builtin_amdgcn_mfma_f32_16x16x32_bf16(kf, ancf, zf4, 0, 0, 0);
      float p0 = expc(fmaf(sv[0], scale1, bia[i][0]) - off1);
      float p1 = expc(fmaf(sv[1], scale1, bia[i][1]) - off1);
      float p2 = expc(fmaf(sv[2], scale1, bia[i][2]) - off1);
      float p3 = expc(fmaf(sv[3], scale1, bia[i][3]) - off1);
      l1 += (p0 + p1) + (p2 + p3);
      uintx2 w; w.x = pk2(p0, p1); w.y = pk2(p2, p3);
      *(uintx2*)(P1T + (i*2 + (quad>>1))*512 + (wv*16 + lane15)*8 + (quad&1)*4) = w;
    }
    asm volatile("s_waitcnt lgkmcnt(0)" ::: "memory");
#pragma unroll
    for (int ks = 0; ks < 4; ++ks){
      short8 ptf = *(const short8*)(P1T + (ks*4 + quad)*512 + (wv*16 + lane15)*8);
#pragma unroll
      for (int m = 0; m < 2; ++m){
        short8 vtf = *(const short8*)(VT + (ks*4 + quad)*256 + (m*16 + lane15)*8);
        accO1[m] = __builtin_amdgcn_mfma_f32_16x16x32_bf16(vtf, ptf, accO1[m], 0, 0, 0);
      }
    }
    __syncthreads();
  }
  l1 = redq(l1);
  int ent = (s*4 + h)*2 + kb;
  if (quad == 0) gl1[ent*64 + wv*16 + lane15] = l1;
#pragma unroll
  for (int m = 0; m < 2; ++m){
    uintx2 w; w.x = pk2(accO1[m][0], accO1[m][1]); w.y = pk2(accO1[m][2], accO1[m][3]);
    *(uintx2*)(gO + (size_t)ent*2048 + (wv*16 + lane15)*32 + m*16 + quad*4) = w;
  }
}

// ---------------- stripe phase 2: xs ----------------
// grid (32 stripes * 4 query-chunks, 4 heads)
__launch_bounds__(256, 3)
__global__ void stripe_xs(const u16* __restrict__ qkvh, const u16* __restrict__ anchor,
                          const float* __restrict__ ls2, const float* __restrict__ bias2,
                          const float* __restrict__ gl1, const u16* __restrict__ gO,
                          float* __restrict__ outm, int r0){
  __shared__ __align__(16) u16 sm[20480]; // ANC[0,2048) XMT[2048,4096) QW[4096+wv*2048) P2T[12288+wv*2048)
  const int tid = threadIdx.x, lane = tid & 63, wv = tid >> 6;
  const int lane15 = lane & 15, quad = lane >> 4;
  const int s = blockIdx.x >> 2, qc = blockIdx.x & 3, h = blockIdx.y;
  const int syl = s >> 3, sx = s & 7;
  u16* ANC = sm;
  u16* XMT = sm + 2048;
  u16* QW  = sm + 4096 + wv*2048;
  u16* P2T = sm + 12288 + wv*2048;
  if (tid < 64){
    int ay = (r0 >> 2) + syl*8 + (tid >> 3), ax = sx*8 + (tid & 7);
    float v[32]; load32(anchor + (size_t)(ay*64 + ax)*128 + h*32, v);
    norm_store(ANC, v, tid, 512);
  }
  { // combine xm partials -> XMT [anchor-oct][d 32][8] bf16
    int a = tid >> 2, db = (tid & 3)*8;
    int e0 = (s*4 + h)*2;
    float inv = 1.f / (gl1[e0*64 + a] + gl1[(e0 + 1)*64 + a]);
    uintx4 u0 = *(const uintx4*)(gO + (size_t)e0*2048 + a*32 + db);
    uintx4 u1 = *(const uintx4*)(gO + (size_t)(e0 + 1)*2048 + a*32 + db);
    unsigned int w0[4] = {u0.x, u0.y, u0.z, u0.w};
    unsigned int w1[4] = {u1.x, u1.y, u1.z, u1.w};
#pragma unroll
    for (int c = 0; c < 4; ++c){
      float a0 = bf2f((u16)(w0[c] & 0xffffu)) + bf2f((u16)(w1[c] & 0xffffu));
      float a1 = bf2f((u16)(w0[c] >> 16))     + bf2f((u16)(w1[c] >> 16));
      XMT[(a >> 3)*256 + (db + c*2)*8     + (a & 7)] = f2bf(a0 * inv);
      XMT[(a >> 3)*256 + (db + c*2 + 1)*8 + (a & 7)] = f2bf(a1 * inv);
    }
  }
  __syncthreads();
  int tq = qc*256 + wv*64;     // query base within stripe (wave owns 64)
  { int tok = tq + lane;
    int pyl = syl*32 + (tok >> 5), px = sx*32 + (tok & 31);
    float v[32]; load32(qkvh + (size_t)(pyl*256 + px)*384 + h*32, v);
    norm_store(QW, v, lane, 512);
  }
  asm volatile("s_waitcnt lgkmcnt(0)" ::: "memory");
  short8 qf2[4];
#pragma unroll
  for (int j = 0; j < 4; ++j)
    qf2[j] = *(const short8*)(QW + quad*512 + (j*16 + lane15)*8);
  float scale2 = __expf(fminf(ls2[h], 4.6051702f));
  float off2 = fminf(scale2 + 16.f, 80.f);
  const float* b2p = bias2 + ((size_t)h << 16);
  const floatx4 zf4 = {0.f, 0.f, 0.f, 0.f};
  floatx4 accO2[2][4] = {};
  float l2[4] = {};
#pragma unroll
  for (int c = 0; c < 2; ++c){      // 2 anchor chunks of 32
    floatx4 bia[2][4];
#pragma unroll
    for (int i = 0; i < 2; ++i)
#pragma unroll
      for (int j = 0; j < 4; ++j)
        bia[i][j] = *(const floatx4*)(b2p + (size_t)(tq + j*16 + lane15)*64 + c*32 + i*16 + quad*4);
    short8 af[2];
#pragma unroll
    for (int i = 0; i < 2; ++i)
      af[i] = *(const short8*)(ANC + quad*512 + (c*32 + i*16 + lane15)*8);
#pragma unroll
    for (int i = 0; i < 2; ++i)
#pragma unroll
      for (int j = 0; j < 4; ++j){
        floatx4 sv = __builtin_amdgcn_mfma_f32_16x16x32_bf16(af[i], qf2[j], zf4, 0, 0, 0);
        float p0 = expc(fmaf(sv[0], scale2, bia[i][j][0]) - off2);
        float p1 = expc(fmaf(sv[1], scale2, bia[i][j][1]) - off2);
        float p2 = expc(fmaf(sv[2], scale2, bia[i][j][2]) - off2);
        float p3 = expc(fmaf(sv[3], scale2, bia[i][j][3]) - off2);
        l2[j] += (p0 + p1) + (p2 + p3);
        uintx2 w; w.x = pk2(p0, p1); w.y = pk2(p2, p3);
        *(uintx2*)(P2T + (i*2 + (quad>>1))*512 + (j*16 + lane15)*8 + (quad&1)*4) = w;
      }
    asm volatile("s_waitcnt lgkmcnt(0)" ::: "memory");
    short8 ptf[4], xmf[2];
#pragma unroll
    for (int j = 0; j < 4; ++j)
      ptf[j] = *(const short8*)(P2T + quad*512 + (j*16 + lane15)*8);
#pragma unroll
    for (int m = 0; m < 2; ++m)
      xmf[m] = *(const short8*)(XMT + (c*4 + quad)*256 + (m*16 + lane15)*8);
#pragma unroll
    for (int m = 0; m < 2; ++m)
#pragma unroll
      for (int j = 0; j < 4; ++j)
        accO2[m][j] = __builtin_amdgcn_mfma_f32_16x16x32_bf16(xmf[m], ptf[j], accO2[m][j], 0, 0, 0);
  }
  float linv[4];
#pragma unroll
  for (int j = 0; j < 4; ++j) linv[j] = 1.f / redq(l2[j]);
#pragma unroll
  for (int m = 0; m < 2; ++m)
#pragma unroll
    for (int j = 0; j < 4; ++j){
      int tok = tq + j*16 + lane15;
      int py = r0 + syl*32 + (tok >> 5), px = sx*32 + (tok & 31);
      floatx4 o = accO2[m][j] * linv[j];
      *(floatx4*)(outm + (size_t)(py*256 + px)*256 + 128 + h*32 + m*16 + quad*4) = o;
    }
}

// ---------------- launch ----------------
extern "C" void kernel_launch(void* const* d_in, const int* in_sizes, int n_in,
                              void* d_out, int out_size, void* d_ws, size_t ws_size,
                              hipStream_t stream) {
  (void)in_sizes; (void)n_in; (void)out_size; (void)ws_size;
  const float* x        = (const float*)d_in[0];
  const float* qkv_w    = (const float*)d_in[1];
  const float* qkv_b    = (const float*)d_in[2];
  const float* anchor_w = (const float*)d_in[3];
  const float* anchor_b = (const float*)d_in[4];
  const float* ls_w     = (const float*)d_in[5];
  const float* w1_w     = (const float*)d_in[6];
  const float* b1_w     = (const float*)d_in[7];
  const float* w2_w     = (const float*)d_in[8];
  const float* ls_s1    = (const float*)d_in[9];
  const float* w1_s1    = (const float*)d_in[10];
  const float* b1_s1    = (const float*)d_in[11];
  const float* w2_s1    = (const float*)d_in[12];
  const float* ls_s2    = (const float*)d_in[13];
  const float* w1_s2    = (const float*)d_in[14];
  const float* b1_s2    = (const float*)d_in[15];
  const float* w2_s2    = (const float*)d_in[16];
  const float* proj_w   = (const float*)d_in[17];
  const float* proj_b   = (const float*)d_in[18];
  const float* table_w  = (const float*)d_in[19];
  const float* table_s  = (const float*)d_in[20];
  const int* index_w   = (const int*)d_in[21];
  const int* index_a2w = (const int*)d_in[22];
  const int* index_w2a = (const int*)d_in[23];

  // ---- workspace layout (31.1 MB peak) ----
  char* ws = (char*)d_ws;
  u16*   qkvh   = (u16*)(ws + 0);                  // 32768*384 bf16 = 25165824 B (reused 4x)
  float* pooled = (float*)(ws + 0);                // 4096*256 f32 = 4 MB; dead before qkvh written
  u16*   anch   = (u16*)(ws + 25165824);           // 4096*128 bf16
  u16*   qkvt   = (u16*)(ws + 26214400);           // 768*256 bf16
  u16*   anct   = (u16*)(ws + 26607616);           // 128*256 bf16
  u16*   projt  = (u16*)(ws + 26673152);           // 256*256 bf16
  float* btw    = (float*)(ws + 26804224);
  float* bts1   = (float*)(ws + 26820608);
  float* bts2   = (float*)(ws + 26845184);
  float* biasw  = (float*)(ws + 26869760);         // 4*256*256 f32
  float* bias1  = (float*)(ws + 27918336);         // 4*64*1024 f32
  float* bias2  = (float*)(ws + 28966912);         // 4*1024*64 f32
  float* gl1    = (float*)(ws + 30015488);         // 256*64 f32 = 64 KB
  u16*   gO     = (u16*)(ws + 30081024);           // 256*2048 bf16 = 1 MB (end 31129600)

  float* merged = (float*)d_out;                   // f32 scratch, then final output (in-place proj)

  transpose_w<<<1152, 256, 0, stream>>>(qkv_w, anchor_w, proj_w, qkvt, anct, projt);
  cpb_mlp<<<dim3(24, 3), 256, 0, stream>>>(table_w, table_s,
                                           w1_w, b1_w, w2_w,
                                           w1_s1, b1_s1, w2_s1,
                                           w1_s2, b1_s2, w2_s2,
                                           btw, bts1, bts2);
  bias_gather<<<3072, 256, 0, stream>>>(btw, bts1, bts2, index_w, index_a2w, index_w2a,
                                        biasw, bias1, bias2);
  avgpool<<<4096, 256, 0, stream>>>(x, pooled);
  gemm_bt<<<dim3(32, 1), 256, 0, stream>>>(pooled, anct, anchor_b, anch, 4096, 128, 256);

  for (int half = 0; half < 2; ++half){
    const float* xh = x + (size_t)half*32768*256;
    int r0 = half*128;
    // window branch, qkv channels [0,384)
    gemm_bt<<<dim3(256, 3), 256, 0, stream>>>(xh, qkvt, qkv_b, qkvh, 32768, 384, 256);
    win_attn<<<dim3(128, 4), 256, 0, stream>>>(qkvh, ls_w, biasw, merged, r0);
    // stripe branch, qkv channels [384,768)
    gemm_bt<<<dim3(256, 3), 256, 0, stream>>>(xh, qkvt + 384*256, qkv_b + 384, qkvh, 32768, 384, 256);
    stripe_xm<<<dim3(32, 4, 2), 256, 0, stream>>>(qkvh, anch, ls_s1, bias1, gl1, gO, r0);
    stripe_xs<<<dim3(128, 4), 256, 0, stream>>>(qkvh, anch, ls_s2, bias2, gl1, gO, merged, r0);
  }

  // output projection, in place on f32 d_out
  gemm_proj_inplace<<<dim3(512), 256, 0, stream>>>(merged, projt, proj_b);
}